// Round 2
// baseline (1613.343 us; speedup 1.0000x reference)
//
#include <hip/hip_runtime.h>
#include <hip/hip_bf16.h>
#include <cstdint>
#include <cstddef>

// Problem constants
#define B_   16
#define S_   4096
#define D_   64
#define TQ   64      // Q rows per block (4 waves x 16)
#define TK   64      // keys per tile iteration
#define NT   (S_ / TK)
#define KSTR 72      // LDS row stride (ushorts) for fallback kernel
#define VSTR 72
#define PSTR 72
#define CTX_ELEMS (B_*S_*D_)   // context floats; attn follows in d_out

typedef __attribute__((ext_vector_type(8))) short short8;  // 8 bf16 = 4 VGPRs
typedef __attribute__((ext_vector_type(4))) float f32x4;

static __device__ __forceinline__ unsigned short f2bf(float f) {
  union { float f; unsigned int u; } v; v.f = f;
  unsigned int r = (v.u + 0x7FFFu + ((v.u >> 16) & 1u)) >> 16;  // RN-even
  return (unsigned short)r;
}

// ---- pre-pass 1: elementwise fp32 -> bf16 (for K) ----
__global__ __launch_bounds__(256) void conv_bf16_kernel(
    const float* __restrict__ src, unsigned short* __restrict__ dst) {
  int i = blockIdx.x * 256 + threadIdx.x;        // handles 8 elems
  const float4* s = (const float4*)src;
  float4 a = s[(size_t)i*2], b = s[(size_t)i*2 + 1];
  unsigned int u0 = (unsigned)f2bf(a.x) | ((unsigned)f2bf(a.y) << 16);
  unsigned int u1 = (unsigned)f2bf(a.z) | ((unsigned)f2bf(a.w) << 16);
  unsigned int u2 = (unsigned)f2bf(b.x) | ((unsigned)f2bf(b.y) << 16);
  unsigned int u3 = (unsigned)f2bf(b.z) | ((unsigned)f2bf(b.w) << 16);
  uint4 o; o.x = u0; o.y = u1; o.z = u2; o.w = u3;
  *(uint4*)(dst + (size_t)i * 8) = o;
}

// ---- pre-pass 2: V [b][k][d] fp32 -> Vt [b][d][k] bf16 (LDS transpose) ----
__global__ __launch_bounds__(256) void convVt_kernel(
    const float* __restrict__ V, unsigned short* __restrict__ Vt) {
  __shared__ unsigned short lsT[D_ * VSTR];
  const int tid = threadIdx.x;
  const int b = blockIdx.y, k0 = blockIdx.x * 64;
  const float4* src = (const float4*)(V + ((size_t)(b * S_ + k0)) * D_);
#pragma unroll
  for (int i = 0; i < 4; ++i) {
    int li = tid + 256 * i;           // 1024 float4 = 64 keys x 16
    int row = li >> 4, c4 = li & 15;  // row = key, c4 = dim group
    float4 v = src[row * 16 + c4];
    lsT[(c4 * 4 + 0) * VSTR + row] = f2bf(v.x);
    lsT[(c4 * 4 + 1) * VSTR + row] = f2bf(v.y);
    lsT[(c4 * 4 + 2) * VSTR + row] = f2bf(v.z);
    lsT[(c4 * 4 + 3) * VSTR + row] = f2bf(v.w);
  }
  __syncthreads();
#pragma unroll
  for (int i = 0; i < 2; ++i) {
    int li = tid + 256 * i;           // 512 x 16B = 64 d-rows x 128 B
    int d = li >> 3, c = li & 7;
    uint4 v = *(const uint4*)&lsT[d * VSTR + c * 8];
    *(uint4*)(Vt + ((size_t)(b * D_ + d)) * S_ + k0 + c * 8) = v;
  }
}

// ================= main fused attention kernel (PRE path) =================
// Barrier-free design: K and Vt fragments are read DIRECTLY from global
// (L1/L2-resident: 512 KB per batch each; each wave's fragment reads are
// contiguous 2 KB bursts shared by all 4 waves -> L1 hits). No lsK/lsV, no
// inter-wave coupling, no per-tile barriers. Only LDS:
//   - lsBias (16 KB, written once, 1 barrier total)
//   - lsP (per-wave P C->A layout round-trip; wave-internal, in-order LDS,
//     lgkmcnt(0) suffices -- no s_barrier)
// QK^T uses swapped operands mfma(K,Q): C row = key, col = query -> each lane
// holds 4 consecutive keys of ONE query -> dwordx4 attn store, packed b64 P
// write, float4 bias broadcast, 2-shuffle denominator reduce.
__global__ __launch_bounds__(256, 4) void attn_pre_kernel(
    const float* __restrict__ Q,
    const unsigned short* __restrict__ K16,
    const unsigned short* __restrict__ Vt16,
    const int* __restrict__ mask,
    float* __restrict__ out) {
  __shared__ unsigned short lsP[4 * 16 * PSTR];   // 9216 B (per-wave P tiles)
  __shared__ __align__(16) float lsBias[S_];      // 16384 B

  const int tid = threadIdx.x;
  const int wave = tid >> 6, lane = tid & 63;
  const int quad = lane >> 4, n = lane & 15;

  // swizzle: 2 batches per XCD (g%8 = XCD round-robin heuristic, perf-only)
  const int g = blockIdx.x;
  const int b = (g & 7) * 2 + ((g >> 3) & 1);
  const int qt = g >> 4;
  const int qbase = qt * TQ;
  const int bS = b * S_;

  // mask -> additive bias for the whole row of keys (once per block)
  {
    const uint4* mi = (const uint4*)(mask + bS);
    float4* bo = (float4*)lsBias;
    for (int i = tid; i < S_ / 4; i += 256) {
      uint4 m = mi[i];
      float4 f;
      f.x = m.x ? -1e30f : 0.0f;
      f.y = m.y ? -1e30f : 0.0f;
      f.z = m.z ? -1e30f : 0.0f;
      f.w = m.w ? -1e30f : 0.0f;
      bo[i] = f;
    }
  }

  // Q fragments (B-operand; A/B fragments share the same lane mapping)
  const float QSC = 0.125f * 1.44269504088896340736f;
  const int qrow = qbase + wave * 16 + n;
  const float* qp = Q + ((size_t)(bS + qrow)) * D_ + quad * 8;
  short8 aq0, aq1;
  {
    float4 f0 = *(const float4*)(qp);
    float4 f1 = *(const float4*)(qp + 4);
    float4 f2 = *(const float4*)(qp + 32);
    float4 f3 = *(const float4*)(qp + 36);
    aq0[0] = (short)f2bf(f0.x * QSC); aq0[1] = (short)f2bf(f0.y * QSC);
    aq0[2] = (short)f2bf(f0.z * QSC); aq0[3] = (short)f2bf(f0.w * QSC);
    aq0[4] = (short)f2bf(f1.x * QSC); aq0[5] = (short)f2bf(f1.y * QSC);
    aq0[6] = (short)f2bf(f1.z * QSC); aq0[7] = (short)f2bf(f1.w * QSC);
    aq1[0] = (short)f2bf(f2.x * QSC); aq1[1] = (short)f2bf(f2.y * QSC);
    aq1[2] = (short)f2bf(f2.z * QSC); aq1[3] = (short)f2bf(f2.w * QSC);
    aq1[4] = (short)f2bf(f3.x * QSC); aq1[5] = (short)f2bf(f3.y * QSC);
    aq1[6] = (short)f2bf(f3.z * QSC); aq1[7] = (short)f2bf(f3.w * QSC);
  }

  __syncthreads();   // lsBias visible to all waves (only barrier in kernel)

  // per-lane K fragment base: row n (+ch*16 per chunk), dims quad*8..+7
  // byte-aligned 16B; a wave's 64 lanes cover 16 consecutive rows x 128 B
  // = contiguous 2 KB -> perfectly coalesced, L1/L2-hit.
  const unsigned short* kb = K16 + ((size_t)bS + n) * D_ + quad * 8;

  // ---------------- sweep 1: denominators (no LDS, no barriers) -----------
  float l0 = 0.f, l1 = 0.f, l2 = 0.f, l3 = 0.f;
  for (int kt = 0; kt < NT; ++kt) {
    const unsigned short* kp = kb + (size_t)(kt * TK) * D_;
    const float4* bp = (const float4*)&lsBias[kt * TK + quad * 4];
#pragma unroll
    for (int ch = 0; ch < 4; ++ch) {
      short8 kb0 = *(const short8*)(kp + ch * 16 * D_);
      short8 kb1 = *(const short8*)(kp + ch * 16 * D_ + 32);
      f32x4 c = {0.f, 0.f, 0.f, 0.f};
      c = __builtin_amdgcn_mfma_f32_16x16x32_bf16(kb0, aq0, c, 0, 0, 0);
      c = __builtin_amdgcn_mfma_f32_16x16x32_bf16(kb1, aq1, c, 0, 0, 0);
      const float4 bb = bp[ch * 4];
      l0 += exp2f(c[0] + bb.x);
      l1 += exp2f(c[1] + bb.y);
      l2 += exp2f(c[2] + bb.z);
      l3 += exp2f(c[3] + bb.w);
    }
  }
  // all 4 regs belong to the SAME query (col n): 2-shuffle quad reduce
  float lt = (l0 + l1) + (l2 + l3);
  lt += __shfl_xor(lt, 16);
  lt += __shfl_xor(lt, 32);
  const float rl = 1.0f / lt;

  // ---------------- sweep 2: attn write + PV (no barriers) ----------------
  f32x4 oc0 = {0.f,0.f,0.f,0.f}, oc1 = {0.f,0.f,0.f,0.f};
  f32x4 oc2 = {0.f,0.f,0.f,0.f}, oc3 = {0.f,0.f,0.f,0.f};
  float* attnRow = out + CTX_ELEMS + ((size_t)(bS + qrow)) * S_;
  // per-lane Vt fragment base: d-row n (+dblk*16), keys k0+ks*32+quad*8
  const unsigned short* vb = Vt16 + ((size_t)(b * D_) + n) * S_ + quad * 8;
  const int prow = (wave * 16 + n) * PSTR;
  for (int kt = 0; kt < NT; ++kt) {
    asm volatile("" ::: "memory");   // compiler fence: keep kt-1 P reads
                                     // ordered before kt P writes
    const int k0 = kt * TK;
    const unsigned short* kp = kb + (size_t)k0 * D_;
#pragma unroll
    for (int ch = 0; ch < 4; ++ch) {
      short8 kb0 = *(const short8*)(kp + ch * 16 * D_);
      short8 kb1 = *(const short8*)(kp + ch * 16 * D_ + 32);
      f32x4 c = {0.f, 0.f, 0.f, 0.f};
      c = __builtin_amdgcn_mfma_f32_16x16x32_bf16(kb0, aq0, c, 0, 0, 0);
      c = __builtin_amdgcn_mfma_f32_16x16x32_bf16(kb1, aq1, c, 0, 0, 0);
      const float4 bb = *(const float4*)&lsBias[k0 + ch * 16 + quad * 4];
      f32x4 p;
      p[0] = exp2f(c[0] + bb.x) * rl;
      p[1] = exp2f(c[1] + bb.y) * rl;
      p[2] = exp2f(c[2] + bb.z) * rl;
      p[3] = exp2f(c[3] + bb.w) * rl;
      // 4 consecutive keys of one query row -> exact fp32 dwordx4 store
      __builtin_nontemporal_store(p, (f32x4*)(attnRow + k0 + ch * 16 + quad * 4));
      // packed bf16 P -> LDS (b64 write), P[q=row][k=col] layout for PV A-frag
      uint2 pw;
      pw.x = (unsigned)f2bf(p[0]) | ((unsigned)f2bf(p[1]) << 16);
      pw.y = (unsigned)f2bf(p[2]) | ((unsigned)f2bf(p[3]) << 16);
      *(uint2*)&lsP[prow + ch * 16 + quad * 4] = pw;
    }
    // wave-internal LDS exchange: own wave's writes drained -> visible to all
    // lanes of this wave (in-order LDS). No s_barrier needed (lsP is per-wave).
    asm volatile("s_waitcnt lgkmcnt(0)" ::: "memory");
    // PV: A = P (LDS round-trip C->A layout), B = Vt rows (contiguous k)
#pragma unroll
    for (int ks = 0; ks < 2; ++ks) {
      short8 ap = *(const short8*)&lsP[prow + ks * 32 + quad * 8];
      short8 bv0 = *(const short8*)(vb + (size_t)(0 * 16) * S_ + k0 + ks * 32);
      short8 bv1 = *(const short8*)(vb + (size_t)(1 * 16) * S_ + k0 + ks * 32);
      short8 bv2 = *(const short8*)(vb + (size_t)(2 * 16) * S_ + k0 + ks * 32);
      short8 bv3 = *(const short8*)(vb + (size_t)(3 * 16) * S_ + k0 + ks * 32);
      oc0 = __builtin_amdgcn_mfma_f32_16x16x32_bf16(ap, bv0, oc0, 0, 0, 0);
      oc1 = __builtin_amdgcn_mfma_f32_16x16x32_bf16(ap, bv1, oc1, 0, 0, 0);
      oc2 = __builtin_amdgcn_mfma_f32_16x16x32_bf16(ap, bv2, oc2, 0, 0, 0);
      oc3 = __builtin_amdgcn_mfma_f32_16x16x32_bf16(ap, bv3, oc3, 0, 0, 0);
    }
  }
  // context write (C-layout: row = quad*4+r, col = dc*16+n)
#pragma unroll
  for (int r = 0; r < 4; ++r) {
    int qr = qbase + wave * 16 + quad * 4 + r;
    float* op = out + ((size_t)(bS + qr)) * D_ + n;
    __builtin_nontemporal_store(oc0[r], op + 0);
    __builtin_nontemporal_store(oc1[r], op + 16);
    __builtin_nontemporal_store(oc2[r], op + 32);
    __builtin_nontemporal_store(oc3[r], op + 48);
  }
}

// ================= fallback kernel (no workspace) =================
// LDS-staged version with __syncthreads; only used if ws_size is too small.
__global__ __launch_bounds__(256, 2) void attn_fb_kernel(
    const float* __restrict__ Q,
    const float* __restrict__ K32,
    const float* __restrict__ V32,
    const int* __restrict__ mask,
    float* __restrict__ out) {
  __shared__ unsigned short lsK[TK * KSTR];
  __shared__ unsigned short lsV[D_ * VSTR];
  __shared__ unsigned short lsP[4 * 16 * PSTR];
  __shared__ __align__(16) float lsBias[S_];

  const int tid = threadIdx.x;
  const int wave = tid >> 6, lane = tid & 63;
  const int quad = lane >> 4, n = lane & 15;

  const int g = blockIdx.x;
  const int b = (g & 7) * 2 + ((g >> 3) & 1);
  const int qt = g >> 4;
  const int qbase = qt * TQ;
  const int bS = b * S_;

  {
    const uint4* mi = (const uint4*)(mask + bS);
    float4* bo = (float4*)lsBias;
    for (int i = tid; i < S_ / 4; i += 256) {
      uint4 m = mi[i];
      float4 f;
      f.x = m.x ? -1e30f : 0.0f;
      f.y = m.y ? -1e30f : 0.0f;
      f.z = m.z ? -1e30f : 0.0f;
      f.w = m.w ? -1e30f : 0.0f;
      bo[i] = f;
    }
  }

  const float QSC = 0.125f * 1.44269504088896340736f;
  const int qrow = qbase + wave * 16 + n;
  const float* qp = Q + ((size_t)(bS + qrow)) * D_ + quad * 8;
  short8 aq0, aq1;
  {
    float4 f0 = *(const float4*)(qp);
    float4 f1 = *(const float4*)(qp + 4);
    float4 f2 = *(const float4*)(qp + 32);
    float4 f3 = *(const float4*)(qp + 36);
    aq0[0] = (short)f2bf(f0.x * QSC); aq0[1] = (short)f2bf(f0.y * QSC);
    aq0[2] = (short)f2bf(f0.z * QSC); aq0[3] = (short)f2bf(f0.w * QSC);
    aq0[4] = (short)f2bf(f1.x * QSC); aq0[5] = (short)f2bf(f1.y * QSC);
    aq0[6] = (short)f2bf(f1.z * QSC); aq0[7] = (short)f2bf(f1.w * QSC);
    aq1[0] = (short)f2bf(f2.x * QSC); aq1[1] = (short)f2bf(f2.y * QSC);
    aq1[2] = (short)f2bf(f2.z * QSC); aq1[3] = (short)f2bf(f2.w * QSC);
    aq1[4] = (short)f2bf(f3.x * QSC); aq1[5] = (short)f2bf(f3.y * QSC);
    aq1[6] = (short)f2bf(f3.z * QSC); aq1[7] = (short)f2bf(f3.w * QSC);
  }

  float l0 = 0.f, l1 = 0.f, l2 = 0.f, l3 = 0.f;
  for (int kt = 0; kt < NT; ++kt) {
    const int k0 = kt * TK;
    __syncthreads();
#pragma unroll
    for (int i = 0; i < 4; ++i) {
      int li = tid + 256 * i;
      int row = li >> 4, c4 = li & 15;
      float4 v = *(const float4*)(K32 + ((size_t)(bS + k0 + row)) * D_ + c4 * 4);
      unsigned int u0 = (unsigned)f2bf(v.x) | ((unsigned)f2bf(v.y) << 16);
      unsigned int u1 = (unsigned)f2bf(v.z) | ((unsigned)f2bf(v.w) << 16);
      uint2 uu; uu.x = u0; uu.y = u1;
      *(uint2*)&lsK[row * KSTR + c4 * 4] = uu;
    }
    __syncthreads();
#pragma unroll
    for (int ch = 0; ch < 4; ++ch) {
      short8 kb0 = *(const short8*)&lsK[(ch * 16 + n) * KSTR + quad * 8];
      short8 kb1 = *(const short8*)&lsK[(ch * 16 + n) * KSTR + 32 + quad * 8];
      f32x4 c = {0.f, 0.f, 0.f, 0.f};
      c = __builtin_amdgcn_mfma_f32_16x16x32_bf16(kb0, aq0, c, 0, 0, 0);
      c = __builtin_amdgcn_mfma_f32_16x16x32_bf16(kb1, aq1, c, 0, 0, 0);
      const float4 bb = *(const float4*)&lsBias[k0 + ch * 16 + quad * 4];
      l0 += exp2f(c[0] + bb.x);
      l1 += exp2f(c[1] + bb.y);
      l2 += exp2f(c[2] + bb.z);
      l3 += exp2f(c[3] + bb.w);
    }
  }
  float lt = (l0 + l1) + (l2 + l3);
  lt += __shfl_xor(lt, 16);
  lt += __shfl_xor(lt, 32);
  const float rl = 1.0f / lt;

  f32x4 oc0 = {0.f,0.f,0.f,0.f}, oc1 = {0.f,0.f,0.f,0.f};
  f32x4 oc2 = {0.f,0.f,0.f,0.f}, oc3 = {0.f,0.f,0.f,0.f};
  float* attnRow = out + CTX_ELEMS + ((size_t)(bS + qrow)) * S_;
  for (int kt = 0; kt < NT; ++kt) {
    const int k0 = kt * TK;
    __syncthreads();
#pragma unroll
    for (int i = 0; i < 4; ++i) {
      int li = tid + 256 * i;
      int row = li >> 4, c4 = li & 15;
      float4 v = *(const float4*)(K32 + ((size_t)(bS + k0 + row)) * D_ + c4 * 4);
      unsigned int u0 = (unsigned)f2bf(v.x) | ((unsigned)f2bf(v.y) << 16);
      unsigned int u1 = (unsigned)f2bf(v.z) | ((unsigned)f2bf(v.w) << 16);
      uint2 uu; uu.x = u0; uu.y = u1;
      *(uint2*)&lsK[row * KSTR + c4 * 4] = uu;
      float4 vv = *(const float4*)(V32 + ((size_t)(bS + k0 + row)) * D_ + c4 * 4);
      lsV[(c4 * 4 + 0) * VSTR + row] = f2bf(vv.x);
      lsV[(c4 * 4 + 1) * VSTR + row] = f2bf(vv.y);
      lsV[(c4 * 4 + 2) * VSTR + row] = f2bf(vv.z);
      lsV[(c4 * 4 + 3) * VSTR + row] = f2bf(vv.w);
    }
    __syncthreads();
#pragma unroll
    for (int ch = 0; ch < 4; ++ch) {
      short8 kb0 = *(const short8*)&lsK[(ch * 16 + n) * KSTR + quad * 8];
      short8 kb1 = *(const short8*)&lsK[(ch * 16 + n) * KSTR + 32 + quad * 8];
      f32x4 c = {0.f, 0.f, 0.f, 0.f};
      c = __builtin_amdgcn_mfma_f32_16x16x32_bf16(kb0, aq0, c, 0, 0, 0);
      c = __builtin_amdgcn_mfma_f32_16x16x32_bf16(kb1, aq1, c, 0, 0, 0);
      const float4 bb = *(const float4*)&lsBias[k0 + ch * 16 + quad * 4];
      f32x4 p;
      p[0] = exp2f(c[0] + bb.x) * rl;
      p[1] = exp2f(c[1] + bb.y) * rl;
      p[2] = exp2f(c[2] + bb.z) * rl;
      p[3] = exp2f(c[3] + bb.w) * rl;
      __builtin_nontemporal_store(p, (f32x4*)(attnRow + k0 + ch * 16 + quad * 4));
      uint2 pw;
      pw.x = (unsigned)f2bf(p[0]) | ((unsigned)f2bf(p[1]) << 16);
      pw.y = (unsigned)f2bf(p[2]) | ((unsigned)f2bf(p[3]) << 16);
      *(uint2*)&lsP[(wave * 16 + n) * PSTR + ch * 16 + quad * 4] = pw;
    }
    asm volatile("s_waitcnt lgkmcnt(0)" ::: "memory");
#pragma unroll
    for (int ks = 0; ks < 2; ++ks) {
      short8 ap = *(const short8*)&lsP[(wave * 16 + n) * PSTR + ks * 32 + quad * 8];
      short8 bv0 = *(const short8*)&lsV[(0 * 16 + n) * VSTR + ks * 32 + quad * 8];
      short8 bv1 = *(const short8*)&lsV[(1 * 16 + n) * VSTR + ks * 32 + quad * 8];
      short8 bv2 = *(const short8*)&lsV[(2 * 16 + n) * VSTR + ks * 32 + quad * 8];
      short8 bv3 = *(const short8*)&lsV[(3 * 16 + n) * VSTR + ks * 32 + quad * 8];
      oc0 = __builtin_amdgcn_mfma_f32_16x16x32_bf16(ap, bv0, oc0, 0, 0, 0);
      oc1 = __builtin_amdgcn_mfma_f32_16x16x32_bf16(ap, bv1, oc1, 0, 0, 0);
      oc2 = __builtin_amdgcn_mfma_f32_16x16x32_bf16(ap, bv2, oc2, 0, 0, 0);
      oc3 = __builtin_amdgcn_mfma_f32_16x16x32_bf16(ap, bv3, oc3, 0, 0, 0);
    }
  }
#pragma unroll
  for (int r = 0; r < 4; ++r) {
    int qr = qbase + wave * 16 + quad * 4 + r;
    float* op = out + ((size_t)(bS + qr)) * D_ + n;
    __builtin_nontemporal_store(oc0[r], op + 0);
    __builtin_nontemporal_store(oc1[r], op + 16);
    __builtin_nontemporal_store(oc2[r], op + 32);
    __builtin_nontemporal_store(oc3[r], op + 48);
  }
}

extern "C" void kernel_launch(void* const* d_in, const int* in_sizes, int n_in,
                              void* d_out, int out_size, void* d_ws, size_t ws_size,
                              hipStream_t stream) {
  const float* q = (const float*)d_in[0];
  const float* k = (const float*)d_in[1];
  const float* v = (const float*)d_in[2];
  const int* mask = (const int*)d_in[3];
  float* out = (float*)d_out;

  const size_t elems = (size_t)B_ * S_ * D_;          // 4194304
  const size_t need = 2 * elems * sizeof(unsigned short);  // 16.8 MB
  if (ws_size >= need) {
    unsigned short* K16 = (unsigned short*)d_ws;
    unsigned short* Vt16 = K16 + elems;
    conv_bf16_kernel<<<(int)(elems / 8 / 256), 256, 0, stream>>>(k, K16);
    convVt_kernel<<<dim3(S_ / 64, B_), 256, 0, stream>>>(v, Vt16);
    attn_pre_kernel<<<B_ * (S_ / TQ), 256, 0, stream>>>(
        q, K16, Vt16, mask, out);
  } else {
    attn_fb_kernel<<<B_ * (S_ / TQ), 256, 0, stream>>>(
        q, k, v, mask, out);
  }
}

// Round 3
// 1282.425 us; speedup vs baseline: 1.2580x; 1.2580x over previous
//
#include <hip/hip_runtime.h>
#include <hip/hip_bf16.h>
#include <cstdint>
#include <cstddef>

// Problem constants
#define B_   16
#define S_   4096
#define D_   64
#define TQ   128     // Q rows per block (8 waves x 16)
#define NW   8       // waves per block
#define TK   64      // keys per tile iteration
#define NT   (S_ / TK)
#define KSTR 72      // LDS row stride (ushorts): 64 + 8 pad -> 144 B
#define VSTR 72
#define PSTR 72
#define CTX_ELEMS (B_*S_*D_)   // context floats; attn follows in d_out

typedef __attribute__((ext_vector_type(8))) short short8;  // 8 bf16 = 4 VGPRs
typedef __attribute__((ext_vector_type(4))) float f32x4;

static __device__ __forceinline__ unsigned short f2bf(float f) {
  union { float f; unsigned int u; } v; v.f = f;
  unsigned int r = (v.u + 0x7FFFu + ((v.u >> 16) & 1u)) >> 16;  // RN-even
  return (unsigned short)r;
}

// ---- pre-pass 1: elementwise fp32 -> bf16 (for K) ----
__global__ __launch_bounds__(256) void conv_bf16_kernel(
    const float* __restrict__ src, unsigned short* __restrict__ dst) {
  int i = blockIdx.x * 256 + threadIdx.x;        // handles 8 elems
  const float4* s = (const float4*)src;
  float4 a = s[(size_t)i*2], b = s[(size_t)i*2 + 1];
  unsigned int u0 = (unsigned)f2bf(a.x) | ((unsigned)f2bf(a.y) << 16);
  unsigned int u1 = (unsigned)f2bf(a.z) | ((unsigned)f2bf(a.w) << 16);
  unsigned int u2 = (unsigned)f2bf(b.x) | ((unsigned)f2bf(b.y) << 16);
  unsigned int u3 = (unsigned)f2bf(b.z) | ((unsigned)f2bf(b.w) << 16);
  uint4 o; o.x = u0; o.y = u1; o.z = u2; o.w = u3;
  *(uint4*)(dst + (size_t)i * 8) = o;
}

// ---- pre-pass 2: V [b][k][d] fp32 -> Vt [b][d][k] bf16 (LDS transpose) ----
__global__ __launch_bounds__(256) void convVt_kernel(
    const float* __restrict__ V, unsigned short* __restrict__ Vt) {
  __shared__ unsigned short lsT[D_ * VSTR];
  const int tid = threadIdx.x;
  const int b = blockIdx.y, k0 = blockIdx.x * 64;
  const float4* src = (const float4*)(V + ((size_t)(b * S_ + k0)) * D_);
#pragma unroll
  for (int i = 0; i < 4; ++i) {
    int li = tid + 256 * i;           // 1024 float4 = 64 keys x 16
    int row = li >> 4, c4 = li & 15;  // row = key, c4 = dim group
    float4 v = src[row * 16 + c4];
    lsT[(c4 * 4 + 0) * VSTR + row] = f2bf(v.x);
    lsT[(c4 * 4 + 1) * VSTR + row] = f2bf(v.y);
    lsT[(c4 * 4 + 2) * VSTR + row] = f2bf(v.z);
    lsT[(c4 * 4 + 3) * VSTR + row] = f2bf(v.w);
  }
  __syncthreads();
#pragma unroll
  for (int i = 0; i < 2; ++i) {
    int li = tid + 256 * i;           // 512 x 16B = 64 d-rows x 128 B
    int d = li >> 3, c = li & 7;
    uint4 v = *(const uint4*)&lsT[d * VSTR + c * 8];
    *(uint4*)(Vt + ((size_t)(b * D_ + d)) * S_ + k0 + c * 8) = v;
  }
}

// One raw barrier per tile. lgkmcnt(0) first drains this wave's ds_writes
// (stage + lsP) so after the barrier every wave's writes are visible.
// NO vmcnt drain: register-prefetch global loads stay in flight (T4/T14).
#define BAR() do { \
    asm volatile("s_waitcnt lgkmcnt(0)" ::: "memory"); \
    __builtin_amdgcn_s_barrier(); \
    asm volatile("" ::: "memory"); \
  } while (0)

// ================= main fused attention kernel (PRE path) =================
// 8 waves x 16 q-rows = 128 q-rows per block; K/V tiles double-buffered in
// LDS -> ONE barrier per tile, writes to the alternate buffer overlap compute
// (dbuf makes intra-iteration op order correctness-irrelevant, so the
// compiler can pipeline freely). Register prefetch keeps one tile of global
// loads in flight across the barrier.
// QK^T uses swapped operands mfma(K,Q): C row = key, col = query -> each lane
// holds 4 consecutive keys of ONE query -> dwordx4 attn store, packed b64 P
// write, float4 bias broadcast, 2-shuffle denominator reduce.
__global__ __launch_bounds__(512, 4) void attn_pre_kernel(
    const float* __restrict__ Q,
    const unsigned short* __restrict__ K16,
    const unsigned short* __restrict__ Vt16,
    const int* __restrict__ mask,
    float* __restrict__ out) {
  __shared__ unsigned short lsK[2][TK * KSTR];    // 2 x 9216 B
  __shared__ unsigned short lsV[2][D_ * VSTR];    // 2 x 9216 B ([d][k])
  __shared__ unsigned short lsP[NW * 16 * PSTR];  // 18432 B (per-wave P tiles)
  __shared__ __align__(16) float lsBias[S_];      // 16384 B   => 70 KB total

  const int tid = threadIdx.x;
  const int wave = tid >> 6, lane = tid & 63;
  const int quad = lane >> 4, n = lane & 15;

  // swizzle: 2 batches per XCD (g%8 = XCD round-robin heuristic, perf-only)
  const int g = blockIdx.x;                 // 0..511
  const int b = (g & 7) * 2 + ((g >> 3) & 1);
  const int qt = g >> 4;                    // 0..31
  const int qbase = qt * TQ;
  const int bS = b * S_;

  // mask -> additive bias for the whole row of keys (once per block)
  {
    const uint4* mi = (const uint4*)(mask + bS);
    float4* bo = (float4*)lsBias;
    for (int i = tid; i < S_ / 4; i += 512) {
      uint4 m = mi[i];
      float4 f;
      f.x = m.x ? -1e30f : 0.0f;
      f.y = m.y ? -1e30f : 0.0f;
      f.z = m.z ? -1e30f : 0.0f;
      f.w = m.w ? -1e30f : 0.0f;
      bo[i] = f;
    }
  }

  // Q fragments (B-operand; A/B fragments share the same lane mapping)
  const float QSC = 0.125f * 1.44269504088896340736f;
  const int qrow = qbase + wave * 16 + n;
  const float* qp = Q + ((size_t)(bS + qrow)) * D_ + quad * 8;
  short8 aq0, aq1;
  {
    float4 f0 = *(const float4*)(qp);
    float4 f1 = *(const float4*)(qp + 4);
    float4 f2 = *(const float4*)(qp + 32);
    float4 f3 = *(const float4*)(qp + 36);
    aq0[0] = (short)f2bf(f0.x * QSC); aq0[1] = (short)f2bf(f0.y * QSC);
    aq0[2] = (short)f2bf(f0.z * QSC); aq0[3] = (short)f2bf(f0.w * QSC);
    aq0[4] = (short)f2bf(f1.x * QSC); aq0[5] = (short)f2bf(f1.y * QSC);
    aq0[6] = (short)f2bf(f1.z * QSC); aq0[7] = (short)f2bf(f1.w * QSC);
    aq1[0] = (short)f2bf(f2.x * QSC); aq1[1] = (short)f2bf(f2.y * QSC);
    aq1[2] = (short)f2bf(f2.z * QSC); aq1[3] = (short)f2bf(f2.w * QSC);
    aq1[4] = (short)f2bf(f3.x * QSC); aq1[5] = (short)f2bf(f3.y * QSC);
    aq1[6] = (short)f2bf(f3.z * QSC); aq1[7] = (short)f2bf(f3.w * QSC);
  }

  // staging lane geometry: 512 threads x 16B = one full 64x128B tile per shot
  const int srow = tid >> 3, sc8 = (tid & 7) * 8;  // srow 0..63, col 0..56
  const unsigned short* Kb = K16 + (size_t)bS * D_;
  const unsigned short* Vb = Vt16 + (size_t)(b * D_) * S_;
  const size_t kOff = (size_t)srow * D_ + sc8;

  // ---------------- sweep 1: denominators ----------------
  float l0 = 0.f, l1 = 0.f, l2 = 0.f, l3 = 0.f;
  uint4 sk = *(const uint4*)(Kb + kOff);                 // tile 0
  *(uint4*)&lsK[0][srow * KSTR + sc8] = sk;
  sk = *(const uint4*)(Kb + (size_t)TK * D_ + kOff);     // tile 1 -> regs
  for (int t = 0; t < NT; ++t) {
    BAR();                                 // tile t visible in lsK[t&1]
    if (t + 1 < NT) {
      *(uint4*)&lsK[(t + 1) & 1][srow * KSTR + sc8] = sk;
      if (t + 2 < NT)
        sk = *(const uint4*)(Kb + (size_t)((t + 2) * TK) * D_ + kOff);
    }
    const unsigned short* Lk = lsK[t & 1];
    const int k0 = t * TK;
#pragma unroll
    for (int ch = 0; ch < 4; ++ch) {
      short8 kb0 = *(const short8*)&Lk[(ch * 16 + n) * KSTR + quad * 8];
      short8 kb1 = *(const short8*)&Lk[(ch * 16 + n) * KSTR + 32 + quad * 8];
      f32x4 c = {0.f, 0.f, 0.f, 0.f};
      __builtin_amdgcn_s_setprio(1);
      c = __builtin_amdgcn_mfma_f32_16x16x32_bf16(kb0, aq0, c, 0, 0, 0);
      c = __builtin_amdgcn_mfma_f32_16x16x32_bf16(kb1, aq1, c, 0, 0, 0);
      __builtin_amdgcn_s_setprio(0);
      const float4 bb = *(const float4*)&lsBias[k0 + ch * 16 + quad * 4];
      l0 += exp2f(c[0] + bb.x);
      l1 += exp2f(c[1] + bb.y);
      l2 += exp2f(c[2] + bb.z);
      l3 += exp2f(c[3] + bb.w);
    }
  }
  // all 4 regs belong to the SAME query (col n): 2-shuffle quad reduce
  float lt = (l0 + l1) + (l2 + l3);
  lt += __shfl_xor(lt, 16);
  lt += __shfl_xor(lt, 32);
  const float rl = 1.0f / lt;

  // ---------------- sweep 2: attn write + PV ----------------
  // Prologue writes lsK[0]/lsV[0]: safe -- any sweep-1 straggler is in its
  // last tile reading lsK[1] (NT even), and lsV is untouched in sweep 1.
  f32x4 oc0 = {0.f,0.f,0.f,0.f}, oc1 = {0.f,0.f,0.f,0.f};
  f32x4 oc2 = {0.f,0.f,0.f,0.f}, oc3 = {0.f,0.f,0.f,0.f};
  float* attnRow = out + CTX_ELEMS + ((size_t)(bS + qrow)) * S_;
  const int prow = (wave * 16 + n) * PSTR;
  sk = *(const uint4*)(Kb + kOff);
  uint4 sv = *(const uint4*)(Vb + (size_t)srow * S_ + sc8);
  *(uint4*)&lsK[0][srow * KSTR + sc8] = sk;
  *(uint4*)&lsV[0][srow * VSTR + sc8] = sv;
  sk = *(const uint4*)(Kb + (size_t)TK * D_ + kOff);
  sv = *(const uint4*)(Vb + (size_t)srow * S_ + TK + sc8);
  for (int t = 0; t < NT; ++t) {
    BAR();                                 // tile t visible in lsK/lsV[t&1]
    if (t + 1 < NT) {
      *(uint4*)&lsK[(t + 1) & 1][srow * KSTR + sc8] = sk;
      *(uint4*)&lsV[(t + 1) & 1][srow * VSTR + sc8] = sv;
      if (t + 2 < NT) {
        sk = *(const uint4*)(Kb + (size_t)((t + 2) * TK) * D_ + kOff);
        sv = *(const uint4*)(Vb + (size_t)srow * S_ + (t + 2) * TK + sc8);
      }
    }
    const unsigned short* Lk = lsK[t & 1];
    const unsigned short* Lv = lsV[t & 1];
    const int k0 = t * TK;
#pragma unroll
    for (int ch = 0; ch < 4; ++ch) {
      short8 kb0 = *(const short8*)&Lk[(ch * 16 + n) * KSTR + quad * 8];
      short8 kb1 = *(const short8*)&Lk[(ch * 16 + n) * KSTR + 32 + quad * 8];
      f32x4 c = {0.f, 0.f, 0.f, 0.f};
      __builtin_amdgcn_s_setprio(1);
      c = __builtin_amdgcn_mfma_f32_16x16x32_bf16(kb0, aq0, c, 0, 0, 0);
      c = __builtin_amdgcn_mfma_f32_16x16x32_bf16(kb1, aq1, c, 0, 0, 0);
      __builtin_amdgcn_s_setprio(0);
      const float4 bb = *(const float4*)&lsBias[k0 + ch * 16 + quad * 4];
      f32x4 p;
      p[0] = exp2f(c[0] + bb.x) * rl;
      p[1] = exp2f(c[1] + bb.y) * rl;
      p[2] = exp2f(c[2] + bb.z) * rl;
      p[3] = exp2f(c[3] + bb.w) * rl;
      // 4 consecutive keys of one query row -> exact fp32 dwordx4 store
      __builtin_nontemporal_store(p, (f32x4*)(attnRow + k0 + ch * 16 + quad * 4));
      // packed bf16 P -> LDS (b64 write), P[q=row][k=col] layout for PV A-frag
      uint2 pw;
      pw.x = (unsigned)f2bf(p[0]) | ((unsigned)f2bf(p[1]) << 16);
      pw.y = (unsigned)f2bf(p[2]) | ((unsigned)f2bf(p[3]) << 16);
      *(uint2*)&lsP[prow + ch * 16 + quad * 4] = pw;
    }
    // wave-internal LDS exchange: own wave's writes drained -> visible to all
    // lanes of this wave (in-order LDS). lsP is wave-private: no s_barrier.
    asm volatile("s_waitcnt lgkmcnt(0)" ::: "memory");
    // PV: A = P (LDS round-trip C->A layout), B = Vt rows (contiguous k)
#pragma unroll
    for (int ks = 0; ks < 2; ++ks) {
      short8 ap = *(const short8*)&lsP[prow + ks * 32 + quad * 8];
      short8 bv0 = *(const short8*)&Lv[(0 * 16 + n) * VSTR + ks * 32 + quad * 8];
      short8 bv1 = *(const short8*)&Lv[(1 * 16 + n) * VSTR + ks * 32 + quad * 8];
      short8 bv2 = *(const short8*)&Lv[(2 * 16 + n) * VSTR + ks * 32 + quad * 8];
      short8 bv3 = *(const short8*)&Lv[(3 * 16 + n) * VSTR + ks * 32 + quad * 8];
      __builtin_amdgcn_s_setprio(1);
      oc0 = __builtin_amdgcn_mfma_f32_16x16x32_bf16(ap, bv0, oc0, 0, 0, 0);
      oc1 = __builtin_amdgcn_mfma_f32_16x16x32_bf16(ap, bv1, oc1, 0, 0, 0);
      oc2 = __builtin_amdgcn_mfma_f32_16x16x32_bf16(ap, bv2, oc2, 0, 0, 0);
      oc3 = __builtin_amdgcn_mfma_f32_16x16x32_bf16(ap, bv3, oc3, 0, 0, 0);
      __builtin_amdgcn_s_setprio(0);
    }
  }
  // context write (C-layout: row = quad*4+r, col = dc*16+n)
#pragma unroll
  for (int r = 0; r < 4; ++r) {
    int qr = qbase + wave * 16 + quad * 4 + r;
    float* op = out + ((size_t)(bS + qr)) * D_ + n;
    __builtin_nontemporal_store(oc0[r], op + 0);
    __builtin_nontemporal_store(oc1[r], op + 16);
    __builtin_nontemporal_store(oc2[r], op + 32);
    __builtin_nontemporal_store(oc3[r], op + 48);
  }
}

// ================= fallback kernel (no workspace) =================
// LDS-staged version with __syncthreads; only used if ws_size is too small.
__global__ __launch_bounds__(256, 2) void attn_fb_kernel(
    const float* __restrict__ Q,
    const float* __restrict__ K32,
    const float* __restrict__ V32,
    const int* __restrict__ mask,
    float* __restrict__ out) {
  __shared__ unsigned short lsK[TK * KSTR];
  __shared__ unsigned short lsV[D_ * VSTR];
  __shared__ unsigned short lsP[4 * 16 * PSTR];
  __shared__ __align__(16) float lsBias[S_];

  const int tid = threadIdx.x;
  const int wave = tid >> 6, lane = tid & 63;
  const int quad = lane >> 4, n = lane & 15;

  const int g = blockIdx.x;
  const int b = (g & 7) * 2 + ((g >> 3) & 1);
  const int qt = g >> 4;
  const int qbase = qt * 64;
  const int bS = b * S_;

  {
    const uint4* mi = (const uint4*)(mask + bS);
    float4* bo = (float4*)lsBias;
    for (int i = tid; i < S_ / 4; i += 256) {
      uint4 m = mi[i];
      float4 f;
      f.x = m.x ? -1e30f : 0.0f;
      f.y = m.y ? -1e30f : 0.0f;
      f.z = m.z ? -1e30f : 0.0f;
      f.w = m.w ? -1e30f : 0.0f;
      bo[i] = f;
    }
  }

  const float QSC = 0.125f * 1.44269504088896340736f;
  const int qrow = qbase + wave * 16 + n;
  const float* qp = Q + ((size_t)(bS + qrow)) * D_ + quad * 8;
  short8 aq0, aq1;
  {
    float4 f0 = *(const float4*)(qp);
    float4 f1 = *(const float4*)(qp + 4);
    float4 f2 = *(const float4*)(qp + 32);
    float4 f3 = *(const float4*)(qp + 36);
    aq0[0] = (short)f2bf(f0.x * QSC); aq0[1] = (short)f2bf(f0.y * QSC);
    aq0[2] = (short)f2bf(f0.z * QSC); aq0[3] = (short)f2bf(f0.w * QSC);
    aq0[4] = (short)f2bf(f1.x * QSC); aq0[5] = (short)f2bf(f1.y * QSC);
    aq0[6] = (short)f2bf(f1.z * QSC); aq0[7] = (short)f2bf(f1.w * QSC);
    aq1[0] = (short)f2bf(f2.x * QSC); aq1[1] = (short)f2bf(f2.y * QSC);
    aq1[2] = (short)f2bf(f2.z * QSC); aq1[3] = (short)f2bf(f2.w * QSC);
    aq1[4] = (short)f2bf(f3.x * QSC); aq1[5] = (short)f2bf(f3.y * QSC);
    aq1[6] = (short)f2bf(f3.z * QSC); aq1[7] = (short)f2bf(f3.w * QSC);
  }

  float l0 = 0.f, l1 = 0.f, l2 = 0.f, l3 = 0.f;
  for (int kt = 0; kt < NT; ++kt) {
    const int k0 = kt * TK;
    __syncthreads();
#pragma unroll
    for (int i = 0; i < 4; ++i) {
      int li = tid + 256 * i;
      int row = li >> 4, c4 = li & 15;
      float4 v = *(const float4*)(K32 + ((size_t)(bS + k0 + row)) * D_ + c4 * 4);
      unsigned int u0 = (unsigned)f2bf(v.x) | ((unsigned)f2bf(v.y) << 16);
      unsigned int u1 = (unsigned)f2bf(v.z) | ((unsigned)f2bf(v.w) << 16);
      uint2 uu; uu.x = u0; uu.y = u1;
      *(uint2*)&lsK[row * KSTR + c4 * 4] = uu;
    }
    __syncthreads();
#pragma unroll
    for (int ch = 0; ch < 4; ++ch) {
      short8 kb0 = *(const short8*)&lsK[(ch * 16 + n) * KSTR + quad * 8];
      short8 kb1 = *(const short8*)&lsK[(ch * 16 + n) * KSTR + 32 + quad * 8];
      f32x4 c = {0.f, 0.f, 0.f, 0.f};
      c = __builtin_amdgcn_mfma_f32_16x16x32_bf16(kb0, aq0, c, 0, 0, 0);
      c = __builtin_amdgcn_mfma_f32_16x16x32_bf16(kb1, aq1, c, 0, 0, 0);
      const float4 bb = *(const float4*)&lsBias[k0 + ch * 16 + quad * 4];
      l0 += exp2f(c[0] + bb.x);
      l1 += exp2f(c[1] + bb.y);
      l2 += exp2f(c[2] + bb.z);
      l3 += exp2f(c[3] + bb.w);
    }
  }
  float lt = (l0 + l1) + (l2 + l3);
  lt += __shfl_xor(lt, 16);
  lt += __shfl_xor(lt, 32);
  const float rl = 1.0f / lt;

  f32x4 oc0 = {0.f,0.f,0.f,0.f}, oc1 = {0.f,0.f,0.f,0.f};
  f32x4 oc2 = {0.f,0.f,0.f,0.f}, oc3 = {0.f,0.f,0.f,0.f};
  float* attnRow = out + CTX_ELEMS + ((size_t)(bS + qrow)) * S_;
  for (int kt = 0; kt < NT; ++kt) {
    const int k0 = kt * TK;
    __syncthreads();
#pragma unroll
    for (int i = 0; i < 4; ++i) {
      int li = tid + 256 * i;
      int row = li >> 4, c4 = li & 15;
      float4 v = *(const float4*)(K32 + ((size_t)(bS + k0 + row)) * D_ + c4 * 4);
      unsigned int u0 = (unsigned)f2bf(v.x) | ((unsigned)f2bf(v.y) << 16);
      unsigned int u1 = (unsigned)f2bf(v.z) | ((unsigned)f2bf(v.w) << 16);
      uint2 uu; uu.x = u0; uu.y = u1;
      *(uint2*)&lsK[row * KSTR + c4 * 4] = uu;
      float4 vv = *(const float4*)(V32 + ((size_t)(bS + k0 + row)) * D_ + c4 * 4);
      lsV[(c4 * 4 + 0) * VSTR + row] = f2bf(vv.x);
      lsV[(c4 * 4 + 1) * VSTR + row] = f2bf(vv.y);
      lsV[(c4 * 4 + 2) * VSTR + row] = f2bf(vv.z);
      lsV[(c4 * 4 + 3) * VSTR + row] = f2bf(vv.w);
    }
    __syncthreads();
#pragma unroll
    for (int ch = 0; ch < 4; ++ch) {
      short8 kb0 = *(const short8*)&lsK[(ch * 16 + n) * KSTR + quad * 8];
      short8 kb1 = *(const short8*)&lsK[(ch * 16 + n) * KSTR + 32 + quad * 8];
      f32x4 c = {0.f, 0.f, 0.f, 0.f};
      c = __builtin_amdgcn_mfma_f32_16x16x32_bf16(kb0, aq0, c, 0, 0, 0);
      c = __builtin_amdgcn_mfma_f32_16x16x32_bf16(kb1, aq1, c, 0, 0, 0);
      const float4 bb = *(const float4*)&lsBias[k0 + ch * 16 + quad * 4];
      f32x4 p;
      p[0] = exp2f(c[0] + bb.x) * rl;
      p[1] = exp2f(c[1] + bb.y) * rl;
      p[2] = exp2f(c[2] + bb.z) * rl;
      p[3] = exp2f(c[3] + bb.w) * rl;
      __builtin_nontemporal_store(p, (f32x4*)(attnRow + k0 + ch * 16 + quad * 4));
      uint2 pw;
      pw.x = (unsigned)f2bf(p[0]) | ((unsigned)f2bf(p[1]) << 16);
      pw.y = (unsigned)f2bf(p[2]) | ((unsigned)f2bf(p[3]) << 16);
      *(uint2*)&lsP[(wave * 16 + n) * PSTR + ch * 16 + quad * 4] = pw;
    }
    asm volatile("s_waitcnt lgkmcnt(0)" ::: "memory");
#pragma unroll
    for (int ks = 0; ks < 2; ++ks) {
      short8 ap = *(const short8*)&lsP[(wave * 16 + n) * PSTR + ks * 32 + quad * 8];
      short8 bv0 = *(const short8*)&lsV[(0 * 16 + n) * VSTR + ks * 32 + quad * 8];
      short8 bv1 = *(const short8*)&lsV[(1 * 16 + n) * VSTR + ks * 32 + quad * 8];
      short8 bv2 = *(const short8*)&lsV[(2 * 16 + n) * VSTR + ks * 32 + quad * 8];
      short8 bv3 = *(const short8*)&lsV[(3 * 16 + n) * VSTR + ks * 32 + quad * 8];
      oc0 = __builtin_amdgcn_mfma_f32_16x16x32_bf16(ap, bv0, oc0, 0, 0, 0);
      oc1 = __builtin_amdgcn_mfma_f32_16x16x32_bf16(ap, bv1, oc1, 0, 0, 0);
      oc2 = __builtin_amdgcn_mfma_f32_16x16x32_bf16(ap, bv2, oc2, 0, 0, 0);
      oc3 = __builtin_amdgcn_mfma_f32_16x16x32_bf16(ap, bv3, oc3, 0, 0, 0);
    }
  }
#pragma unroll
  for (int r = 0; r < 4; ++r) {
    int qr = qbase + wave * 16 + quad * 4 + r;
    float* op = out + ((size_t)(bS + qr)) * D_ + n;
    __builtin_nontemporal_store(oc0[r], op + 0);
    __builtin_nontemporal_store(oc1[r], op + 16);
    __builtin_nontemporal_store(oc2[r], op + 32);
    __builtin_nontemporal_store(oc3[r], op + 48);
  }
}

extern "C" void kernel_launch(void* const* d_in, const int* in_sizes, int n_in,
                              void* d_out, int out_size, void* d_ws, size_t ws_size,
                              hipStream_t stream) {
  const float* q = (const float*)d_in[0];
  const float* k = (const float*)d_in[1];
  const float* v = (const float*)d_in[2];
  const int* mask = (const int*)d_in[3];
  float* out = (float*)d_out;

  const size_t elems = (size_t)B_ * S_ * D_;          // 4194304
  const size_t need = 2 * elems * sizeof(unsigned short);  // 16.8 MB
  if (ws_size >= need) {
    unsigned short* K16 = (unsigned short*)d_ws;
    unsigned short* Vt16 = K16 + elems;
    conv_bf16_kernel<<<(int)(elems / 8 / 256), 256, 0, stream>>>(k, K16);
    convVt_kernel<<<dim3(S_ / 64, B_), 256, 0, stream>>>(v, Vt16);
    attn_pre_kernel<<<B_ * (S_ / TQ), 512, 0, stream>>>(
        q, K16, Vt16, mask, out);
  } else {
    attn_fb_kernel<<<B_ * (S_ / 64), 256, 0, stream>>>(
        q, k, v, mask, out);
  }
}